// Round 17
// baseline (317.819 us; speedup 1.0000x reference)
//
#include <hip/hip_runtime.h>

#define T_STEPS 512
#define HID 128
#define ROWS 16   // batch rows per sequence
#define SEQS 2    // sequences per block (wave-split) -> 32 blocks

typedef short bf16x8 __attribute__((ext_vector_type(8)));   // MFMA A/B frag
typedef float f32x4  __attribute__((ext_vector_type(4)));   // MFMA C/D frag
typedef unsigned int u32;
typedef u32 u32x4 __attribute__((ext_vector_type(4)));

// 1024 threads = 16 waves = 4 waves/SIMD. Waves 0-7: seqA, waves 8-15: seqB.
// Each wave = R13's minimal body (8 MFMA + 4 ds_read_b128 + 1 ds_write).
// Cross-wave interleave: seqA/seqB waves share no data -> 4 runnable waves
// per SIMD with staggered stalls; one barrier interval advances TWO steps.
// (R14 proved within-stream seq-interleave fails; this is the cross-wave cell.)
// Slot-major h layout (R16, conflict-free reads) + x prefetch (R13) restored;
// no setprio (harmful in lockstep, R16/m190).

__device__ __forceinline__ u32 cvt_pk_bf16(float s0, float s1) {
    u32 d;  // d.lo = bf16(s0), d.hi = bf16(s1)
    asm("v_cvt_pk_bf16_f32 %0, %1, %2" : "=v"(d) : "v"(s0), "v"(s1));
    return d;
}
__device__ __forceinline__ bf16x8 frag_from(u32 a, u32 b, u32 c, u32 d) {
    u32x4 t = {a, b, c, d};
    return __builtin_bit_cast(bf16x8, t);
}
// tanh(a) = 1 - 2/(exp2(2a*log2e)+1); saturates correctly at +-inf
__device__ __forceinline__ float tanh_fast(float a) {
    const float e  = __builtin_amdgcn_exp2f(a * 2.885390081777926816f);
    const float rc = __builtin_amdgcn_rcpf(e + 1.0f);
    return fmaf(-2.0f, rc, 1.0f);
}

// split 8 f32 into hi/lo bf16 frags (W ~= WH + WL, residual ~2^-18 rel)
#define SPLIT8(HI, LO, fa, fb) do {                                           \
    u32 h0_ = cvt_pk_bf16(fa.x,fa.y), h1_ = cvt_pk_bf16(fa.z,fa.w);           \
    u32 h2_ = cvt_pk_bf16(fb.x,fb.y), h3_ = cvt_pk_bf16(fb.z,fb.w);           \
    float l0_ = fa.x - __uint_as_float(h0_ << 16);                            \
    float l1_ = fa.y - __uint_as_float(h0_ & 0xffff0000u);                    \
    float l2_ = fa.z - __uint_as_float(h1_ << 16);                            \
    float l3_ = fa.w - __uint_as_float(h1_ & 0xffff0000u);                    \
    float l4_ = fb.x - __uint_as_float(h2_ << 16);                            \
    float l5_ = fb.y - __uint_as_float(h2_ & 0xffff0000u);                    \
    float l6_ = fb.z - __uint_as_float(h3_ << 16);                            \
    float l7_ = fb.w - __uint_as_float(h3_ & 0xffff0000u);                    \
    u32 g0_ = cvt_pk_bf16(l0_,l1_), g1_ = cvt_pk_bf16(l2_,l3_);               \
    u32 g2_ = cvt_pk_bf16(l4_,l5_), g3_ = cvt_pk_bf16(l6_,l7_);               \
    HI = frag_from(h0_,h1_,h2_,h3_); LO = frag_from(g0_,g1_,g2_,g3_);         \
} while (0)

#define MFMA(ACC, A, B) \
    ACC = __builtin_amdgcn_mfma_f32_16x16x32_bf16(A, B, ACC, 0, 0, 0);

// LDS: seq s h buffers at s*8192 (+parity*4096), slot-major (R16 layout);
//      red @16384 ([2 s][8 wv][16 r] f32)
#define LDS_BYTES (16384 + 1024)

__global__ __launch_bounds__(1024)
__attribute__((amdgpu_waves_per_eu(4, 4)))
void rnn_mfma_x2w_kernel(const float* __restrict__ x,
                         const float* __restrict__ W_ih,
                         const float* __restrict__ W_hh,
                         const float* __restrict__ b_ih,
                         const float* __restrict__ b_hh,
                         const float* __restrict__ W_out,
                         const float* __restrict__ b_out,
                         float* __restrict__ y)
{
    __shared__ __align__(16) char lds[LDS_BYTES];

    const int tid = threadIdx.x;
    const int w   = tid >> 6;        // wave 0..15
    const int s   = w >> 3;          // sequence 0/1
    const int wv  = w & 7;           // j-tile [16wv, 16wv+16) within the seq
    const int l   = tid & 63;
    const int q   = l >> 4;          // lane quarter (k-group / C row group)
    const int r   = l & 15;          // batch row within seq (A row/B col/C col)
    const int b0  = blockIdx.x * (SEQS * ROWS);
    const u32 sb  = (u32)s * 8192u;  // this seq's LDS base

    // ---- zero both seqs' h buf0 (2 x 4 KB, 1024 threads x 8 B)
    *(uint2*)&lds[(tid >> 9) * 8192 + (tid & 511) * 8] = make_uint2(0u, 0u);

    // ---- W_hh A-frags for j-tile wv: lane(q,r) holds A[m=r][k=32c+8q+e]
    bf16x8 WH0, WH1, WH2, WH3, WL0, WL1, WL2, WL3;
    {
        const float* p = W_hh + (size_t)(16 * wv + r) * HID + 8 * q;
        float4 fa, fb;
        fa = *(const float4*)(p +  0); fb = *(const float4*)(p +   4); SPLIT8(WH0, WL0, fa, fb);
        fa = *(const float4*)(p + 32); fb = *(const float4*)(p +  36); SPLIT8(WH1, WL1, fa, fb);
        fa = *(const float4*)(p + 64); fb = *(const float4*)(p +  68); SPLIT8(WH2, WL2, fa, fb);
        fa = *(const float4*)(p + 96); fb = *(const float4*)(p + 100); SPLIT8(WH3, WL3, fa, fb);
    }

    // ---- per-lane constants for this lane's 4 outputs j0..j0+3
    const int j0 = 16 * wv + 4 * q;
    const float4 wih = *(const float4*)(W_ih + j0);
    float4 bias;
    {
        const float4 bi = *(const float4*)(b_ih + j0);
        const float4 bh = *(const float4*)(b_hh + j0);
        bias.x = bi.x + bh.x; bias.y = bi.y + bh.y;
        bias.z = bi.z + bh.z; bias.w = bi.w + bh.w;
    }

    // ---- slot-major LDS offsets (verified R16: identical absmax to R13)
    const int rswz  = ((r >> 3) << 4) ^ ((q & 1) << 5);
    const int roff0 = ((l * 16) ^ rswz);
    const int cw    = j0 >> 5;
    const int qw    = (j0 >> 3) & 3;
    const int woff  = cw * 1024 +
        ((((qw * 16 + r) * 16) + (j0 & 7) * 2) ^ ((r >> 3) << 4) ^ ((qw & 1) << 5));

    const float* __restrict__ xrow = x + (size_t)(b0 + s * ROWS + r) * T_STEPS;
    float xt = xrow[0];
    f32x4 hv;

    __syncthreads();

    u32 rb = 0, wb = 4096;
    for (int t = 0; t < T_STEPS; ++t) {
        const bf16x8 B0 = *(const bf16x8*)&lds[sb + rb + roff0];
        const bf16x8 B1 = *(const bf16x8*)&lds[sb + rb + roff0 + 1024];
        const bf16x8 B2 = *(const bf16x8*)&lds[sb + rb + roff0 + 2048];
        const bf16x8 B3 = *(const bf16x8*)&lds[sb + rb + roff0 + 3072];
        const float xn = xrow[(t < T_STEPS - 1) ? t + 1 : T_STEPS - 1];

        f32x4 a0, a1, a2, a3;
        a0[0] = fmaf(xt, wih.x, bias.x); a0[1] = fmaf(xt, wih.y, bias.y);
        a0[2] = fmaf(xt, wih.z, bias.z); a0[3] = fmaf(xt, wih.w, bias.w);
        a1 = (f32x4)(0.0f); a2 = (f32x4)(0.0f); a3 = (f32x4)(0.0f);

        // 8 MFMAs, 4 independent chains of depth 2
        MFMA(a0, WH0, B0) MFMA(a1, WH1, B1) MFMA(a2, WH2, B2) MFMA(a3, WH3, B3)
        MFMA(a0, WL0, B0) MFMA(a1, WL1, B1) MFMA(a2, WL2, B2) MFMA(a3, WL3, B3)

        const f32x4 sum = (a0 + a1) + (a2 + a3);
        hv[0] = tanh_fast(sum[0]); hv[1] = tanh_fast(sum[1]);
        hv[2] = tanh_fast(sum[2]); hv[3] = tanh_fast(sum[3]);

        *(uint2*)&lds[sb + wb + woff] =
            make_uint2(cvt_pk_bf16(hv[0], hv[1]), cvt_pk_bf16(hv[2], hv[3]));

        xt = xn;
        rb ^= 4096; wb ^= 4096;
        __syncthreads();
    }

    // ---- y = h_last . W_out + b_out (per seq)
    const float4 wo = *(const float4*)(W_out + j0);
    float v = wo.x*hv[0] + wo.y*hv[1] + wo.z*hv[2] + wo.w*hv[3];
    v += __shfl_xor(v, 16, 64);
    v += __shfl_xor(v, 32, 64);          // lane r: sum over this tile's 16 j
    if (l < 16) *(float*)&lds[16384 + s * 512 + (wv * 16 + r) * 4] = v;
    __syncthreads();
    if (tid < 32) {
        const int ss = tid >> 4, rr = tid & 15;
        float acc = 0.0f;
        #pragma unroll
        for (int ww = 0; ww < 8; ++ww)
            acc += *(const float*)&lds[16384 + ss * 512 + (ww * 16 + rr) * 4];
        y[b0 + ss * ROWS + rr] = acc + b_out[0];
    }
}

extern "C" void kernel_launch(void* const* d_in, const int* in_sizes, int n_in,
                              void* d_out, int out_size, void* d_ws, size_t ws_size,
                              hipStream_t stream)
{
    const float* x     = (const float*)d_in[0];
    const float* W_ih  = (const float*)d_in[1];
    const float* W_hh  = (const float*)d_in[2];
    const float* b_ih  = (const float*)d_in[3];
    const float* b_hh  = (const float*)d_in[4];
    const float* W_out = (const float*)d_in[5];
    const float* b_out = (const float*)d_in[6];
    float* y = (float*)d_out;

    const int B = in_sizes[0] / T_STEPS;   // 1024
    rnn_mfma_x2w_kernel<<<B / (SEQS * ROWS), 1024, 0, stream>>>(
        x, W_ih, W_hh, b_ih, b_hh, W_out, b_out, y);
}

// Round 18
// 164.548 us; speedup vs baseline: 1.9315x; 1.9315x over previous
//
#include <hip/hip_runtime.h>

#define T_STEPS 512
#define HID 128
#define ROWS 16   // batch rows per block -> 64 blocks

typedef short bf16x8 __attribute__((ext_vector_type(8)));   // MFMA A/B frag
typedef float f32x4  __attribute__((ext_vector_type(4)));   // MFMA C/D frag
typedef unsigned int u32;
typedef u32 u32x4 __attribute__((ext_vector_type(4)));

// R13/R16 structure (512 thr = 8 waves = 2/SIMD, 8 MFMA/wave) + VALU DIET:
// R17 counters proved VALU (418cy/SIMD) + MFMA (250cy) fully serialize under
// barrier lockstep, VALU dominated by AGPR<->VGPR shuttles on the accs.
// Fix: (1) ALL W-MFMAs chain into ONE acc (HW forwards same-dst at issue
// rate, m119); (2) bias + x*W_ih folded into a 9th MFMA (A'/B' trick below)
// so the acc is NEVER touched by VALU (C-in = literal zero, 4 final reads
// only); (3) slot-major conflict-free h layout (R16) + x prefetch restored
// (its loss was R16's regression); no setprio (m190).
// Bias-MFMA slots (k=e, q==0 lanes only):
//   e=0: bias_hi*1   e=1: Wih_hi*xhi  e=2: Wih_lo*xhi
//   e=3: Wih_hi*xlo  e=4: bias_lo*1   e>=5: 0

__device__ __forceinline__ u32 cvt_pk_bf16(float s0, float s1) {
    u32 d;  // d.lo = bf16(s0), d.hi = bf16(s1)
    asm("v_cvt_pk_bf16_f32 %0, %1, %2" : "=v"(d) : "v"(s0), "v"(s1));
    return d;
}
__device__ __forceinline__ bf16x8 frag_from(u32 a, u32 b, u32 c, u32 d) {
    u32x4 t = {a, b, c, d};
    return __builtin_bit_cast(bf16x8, t);
}
// tanh(a) = 1 - 2/(exp2(2a*log2e)+1); saturates correctly at +-inf
__device__ __forceinline__ float tanh_fast(float a) {
    const float e  = __builtin_amdgcn_exp2f(a * 2.885390081777926816f);
    const float rc = __builtin_amdgcn_rcpf(e + 1.0f);
    return fmaf(-2.0f, rc, 1.0f);
}

// split 8 f32 into hi/lo bf16 frags (W ~= WH + WL, residual ~2^-18 rel)
#define SPLIT8(HI, LO, fa, fb) do {                                           \
    u32 h0_ = cvt_pk_bf16(fa.x,fa.y), h1_ = cvt_pk_bf16(fa.z,fa.w);           \
    u32 h2_ = cvt_pk_bf16(fb.x,fb.y), h3_ = cvt_pk_bf16(fb.z,fb.w);           \
    float l0_ = fa.x - __uint_as_float(h0_ << 16);                            \
    float l1_ = fa.y - __uint_as_float(h0_ & 0xffff0000u);                    \
    float l2_ = fa.z - __uint_as_float(h1_ << 16);                            \
    float l3_ = fa.w - __uint_as_float(h1_ & 0xffff0000u);                    \
    float l4_ = fb.x - __uint_as_float(h2_ << 16);                            \
    float l5_ = fb.y - __uint_as_float(h2_ & 0xffff0000u);                    \
    float l6_ = fb.z - __uint_as_float(h3_ << 16);                            \
    float l7_ = fb.w - __uint_as_float(h3_ & 0xffff0000u);                    \
    u32 g0_ = cvt_pk_bf16(l0_,l1_), g1_ = cvt_pk_bf16(l2_,l3_);               \
    u32 g2_ = cvt_pk_bf16(l4_,l5_), g3_ = cvt_pk_bf16(l6_,l7_);               \
    HI = frag_from(h0_,h1_,h2_,h3_); LO = frag_from(g0_,g1_,g2_,g3_);         \
} while (0)

#define MFMA(ACC, A, B) \
    ACC = __builtin_amdgcn_mfma_f32_16x16x32_bf16(A, B, ACC, 0, 0, 0);

// LDS: h buf0 @0, h buf1 @4096 (slot-major, R16-verified); red @8192
#define LDS_BYTES (8192 + 512)

__global__ __launch_bounds__(512, 1)
__attribute__((amdgpu_waves_per_eu(2, 2)))
void rnn_diet_kernel(const float* __restrict__ x,
                     const float* __restrict__ W_ih,
                     const float* __restrict__ W_hh,
                     const float* __restrict__ b_ih,
                     const float* __restrict__ b_hh,
                     const float* __restrict__ W_out,
                     const float* __restrict__ b_out,
                     float* __restrict__ y)
{
    __shared__ __align__(16) char lds[LDS_BYTES];

    const int tid = threadIdx.x;
    const int w   = tid >> 6;        // wave 0..7: j-tile [16w, 16w+16)
    const int l   = tid & 63;
    const int q   = l >> 4;          // lane quarter (k-group / C row group)
    const int r   = l & 15;          // batch row (A row m / B col n / C col n)
    const int b0  = blockIdx.x * ROWS;

    // ---- zero h buf0 (4 KB, 512 threads x 8 B)
    *(uint2*)&lds[tid * 8] = make_uint2(0u, 0u);

    // ---- W_hh A-frags for tile w: lane(q,r) holds A[m=r][k=8q+e + 32c]
    bf16x8 WH0, WH1, WH2, WH3, WL0, WL1, WL2, WL3;
    {
        const float* p = W_hh + (size_t)(16 * w + r) * HID + 8 * q;
        float4 fa, fb;
        fa = *(const float4*)(p +  0); fb = *(const float4*)(p +   4); SPLIT8(WH0, WL0, fa, fb);
        fa = *(const float4*)(p + 32); fb = *(const float4*)(p +  36); SPLIT8(WH1, WL1, fa, fb);
        fa = *(const float4*)(p + 64); fb = *(const float4*)(p +  68); SPLIT8(WH2, WL2, fa, fb);
        fa = *(const float4*)(p + 96); fb = *(const float4*)(p + 100); SPLIT8(WH3, WL3, fa, fb);
    }

    // ---- bias/x MFMA A'-frag (hoisted; only q==0 lanes nonzero)
    bf16x8 Ap;
    {
        const int jA = 16 * w + r;               // this lane's A-row j
        const float bias = b_ih[jA] + b_hh[jA];
        const float wih  = W_ih[jA];
        const float bm   = (q == 0) ? bias : 0.0f;
        const float wm   = (q == 0) ? wih  : 0.0f;
        const u32 w0 = cvt_pk_bf16(bm, wm);                       // e0,e1
        const float wl = wm - __uint_as_float(w0 & 0xffff0000u);
        const float bl = bm - __uint_as_float(w0 << 16);
        const u32 w1 = cvt_pk_bf16(wl, wm);                       // e2,e3
        const u32 w2 = cvt_pk_bf16(bl, 0.0f);                     // e4,e5
        Ap = frag_from(w0, w1, w2, 0u);
    }
    const float one_m  = (q == 0) ? 1.0f : 0.0f;
    const u32   bpw2   = cvt_pk_bf16(one_m, 0.0f);   // B' word2 (e4=1)

    // ---- per-lane C/D constants for epilogue (j0..j0+3 of this lane)
    const int j0 = 16 * w + 4 * q;

    // ---- slot-major LDS offsets (R16-verified)
    const int rswz  = ((r >> 3) << 4) ^ ((q & 1) << 5);
    const int roff0 = ((l * 16) ^ rswz);
    const int cw    = j0 >> 5;
    const int qw    = (j0 >> 3) & 3;
    const int woff  = cw * 1024 +
        ((((qw * 16 + r) * 16) + (j0 & 7) * 2) ^ ((r >> 3) << 4) ^ ((qw & 1) << 5));

    const float* __restrict__ xrow = x + (size_t)(b0 + r) * T_STEPS;
    float xt = xrow[0];
    f32x4 hv;

    __syncthreads();

#define STEP(RB, WB, TN) do {                                                 \
    const bf16x8 B0 = *(const bf16x8*)&lds[(RB) + roff0];                     \
    const bf16x8 B1 = *(const bf16x8*)&lds[(RB) + roff0 + 1024];              \
    const bf16x8 B2 = *(const bf16x8*)&lds[(RB) + roff0 + 2048];              \
    const bf16x8 B3 = *(const bf16x8*)&lds[(RB) + roff0 + 3072];              \
    const float xn = xrow[TN];                                                \
    /* B' build: [1, xhi | xhi, xlo | 1, 0 | 0] (q==0 lanes), ~5 VALU */      \
    const float xm   = (q == 0) ? xt : 0.0f;                                  \
    const u32   bw0  = cvt_pk_bf16(one_m, xm);                                \
    const float xhif = __uint_as_float(bw0 & 0xffff0000u);                    \
    const float xlo  = xm - xhif;                                             \
    const u32   bw1  = cvt_pk_bf16(xhif, xlo);                                \
    const bf16x8 Bp  = frag_from(bw0, bw1, bpw2, 0u);                         \
    /* 9-deep same-acc MFMA chain: acc never touched by VALU */               \
    f32x4 acc = __builtin_amdgcn_mfma_f32_16x16x32_bf16(                      \
        Ap, Bp, (f32x4)(0.0f), 0, 0, 0);                                      \
    MFMA(acc, WH0, B0) MFMA(acc, WH1, B1)                                     \
    MFMA(acc, WH2, B2) MFMA(acc, WH3, B3)                                     \
    MFMA(acc, WL0, B0) MFMA(acc, WL1, B1)                                     \
    MFMA(acc, WL2, B2) MFMA(acc, WL3, B3)                                     \
    hv[0] = tanh_fast(acc[0]); hv[1] = tanh_fast(acc[1]);                     \
    hv[2] = tanh_fast(acc[2]); hv[3] = tanh_fast(acc[3]);                     \
    *(uint2*)&lds[(WB) + woff] =                                              \
        make_uint2(cvt_pk_bf16(hv[0], hv[1]), cvt_pk_bf16(hv[2], hv[3]));     \
    xt = xn;                                                                  \
    __syncthreads();                                                          \
} while (0)

    for (int t = 0; t < T_STEPS; t += 2) {
        STEP(0,    4096, t + 1);
        STEP(4096, 0,    (t + 2 < T_STEPS) ? t + 2 : T_STEPS - 1);
    }
#undef STEP

    // ---- y[b0+r] = sum_j W_out[j] * h_last[j] + b_out
    const float4 wo = *(const float4*)(W_out + j0);
    float v = wo.x*hv[0] + wo.y*hv[1] + wo.z*hv[2] + wo.w*hv[3];
    v += __shfl_xor(v, 16, 64);
    v += __shfl_xor(v, 32, 64);          // lane r: sum over this tile's 16 j
    if (l < 16) *(float*)&lds[8192 + (w * 16 + r) * 4] = v;
    __syncthreads();
    if (tid < 16) {
        float s = 0.0f;
        #pragma unroll
        for (int ww = 0; ww < 8; ++ww)
            s += *(const float*)&lds[8192 + (ww * 16 + tid) * 4];
        y[b0 + tid] = s + b_out[0];
    }
}

extern "C" void kernel_launch(void* const* d_in, const int* in_sizes, int n_in,
                              void* d_out, int out_size, void* d_ws, size_t ws_size,
                              hipStream_t stream)
{
    const float* x     = (const float*)d_in[0];
    const float* W_ih  = (const float*)d_in[1];
    const float* W_hh  = (const float*)d_in[2];
    const float* b_ih  = (const float*)d_in[3];
    const float* b_hh  = (const float*)d_in[4];
    const float* W_out = (const float*)d_in[5];
    const float* b_out = (const float*)d_in[6];
    float* y = (float*)d_out;

    const int B = in_sizes[0] / T_STEPS;   // 1024
    rnn_diet_kernel<<<B / ROWS, 512, 0, stream>>>(x, W_ih, W_hh, b_ih, b_hh,
                                                  W_out, b_out, y);
}